// Round 5
// baseline (140.883 us; speedup 1.0000x reference)
//
#include <hip/hip_runtime.h>
#include <stdint.h>
#include <stddef.h>

// ---- problem constants ----
#define K_CODES 1024
#define D_DIM   256
#define HW      1024      // 32*32 spatial
#define N_VEC   32768
#define TOT_ELEMS 8388608

typedef float    v4f __attribute__((ext_vector_type(4)));
typedef _Float16 v8h __attribute__((ext_vector_type(8)));

// async global->LDS, 16B/lane, dest = wave-uniform base + lane*16
__device__ __forceinline__ void gld_lds16(const void* g, void* l) {
    __builtin_amdgcn_global_load_lds(
        (const __attribute__((address_space(1))) void*)g,
        (__attribute__((address_space(3))) void*)l, 16, 0, 0);
}

// ------------------------------------------------------------------
// K1: codebook -> fp16 copy + 0.5*||e||^2
__global__ void prep_emb(const float* __restrict__ emb,
                         _Float16* __restrict__ emb_h,
                         float* __restrict__ hnorm) {
    int k = blockIdx.x, t = threadIdx.x;
    float v = emb[(size_t)k * D_DIM + t];
    emb_h[(size_t)k * D_DIM + t] = (_Float16)v;
    float s = v * v;
    for (int off = 32; off; off >>= 1) s += __shfl_down(s, off);
    __shared__ float wsum[4];
    if ((t & 63) == 0) wsum[t >> 6] = s;
    __syncthreads();
    if (t == 0) hnorm[k] = 0.5f * (wsum[0] + wsum[1] + wsum[2] + wsum[3]);
}

// ------------------------------------------------------------------
// K2: fully fused VQ. 256 blocks x 512 thr (8 waves); LDS ~70 KB so
// 2 blocks/CU co-reside -> 4 waves/SIMD (cross-block latency hiding).
// Intra-block K-split x2: waves 0-3 scan codes 0-511, waves 4-7 codes
// 512-1023, same 128 rows; LDS merge. dist' = 0.5||e||^2 - <z,e>.
// Staging tiles: 32 codes (16 KB), double-buffered per K-group.
// Swizzle: granule g of code k stored at slot u = g ^ (k&7).
__global__ __launch_bounds__(512, 4) void
vq_main(const float* __restrict__ z,
        const _Float16* __restrict__ emb_h,
        const float* __restrict__ emb,
        const float* __restrict__ hnorm,
        float* __restrict__ out,
        float* __restrict__ loss_acc) {
    // [0,65536): btile[2grp][2buf][16KB]   | epilogue zq overlay
    // [65536,69632): norm_s[1024] floats   | (zq spills into it; norms dead)
    __shared__ __align__(16) char smem[69632];
    __shared__ int    idx_s[128];
    __shared__ float2 mrg[4][32];
    __shared__ float  wred[8];

    float* norm_s = (float*)(smem + 65536);

    int t    = threadIdx.x;
    int wave = t >> 6;
    int lane = t & 63;
    int grp  = wave >> 2;     // K-half
    int wv   = wave & 3;      // row-tile selector
    int col  = lane & 15;
    int quad = lane >> 4;
    int b    = blockIdx.x >> 3;
    int hw0  = (blockIdx.x & 7) * 128;
    const float* zb = z + (size_t)b * D_DIM * HW;

    // stage 32-code tile T (16 KB) of this wave's K-half
    auto stage = [&](int buf, int T) {
        const char* src = (const char*)(emb_h
                          + (size_t)(grp * 512 + T * 32) * D_DIM);
        char* dst = smem + (grp * 2 + buf) * 16384 + wv * 4096;
#pragma unroll
        for (int i = 0; i < 4; ++i) {
            int k = wv * 8 + i * 2 + (lane >> 5);
            int g = (lane & 31) ^ (k & 7);
            gld_lds16(src + (size_t)k * 512 + (size_t)g * 16, dst + i * 1024);
        }
    };
    stage(0, 0);

    for (int i = t; i < K_CODES; i += 512) norm_s[i] = hnorm[i];

    // A fragments (32 rows/wave; both K-halves load same rows)
    int m0w = hw0 + wv * 32;
    v8h af0[8], af1[8];
#pragma unroll
    for (int c = 0; c < 8; ++c) {
#pragma unroll
        for (int j = 0; j < 8; ++j) {
            int d = c * 32 + quad * 8 + j;
            const float* p = zb + (size_t)d * HW + m0w + col;
            af0[c][j] = (_Float16)p[0];
            af1[c][j] = (_Float16)p[16];
        }
    }

    float minv[8]; int mini[8];
#pragma unroll
    for (int r = 0; r < 8; ++r) { minv[r] = 3.4e38f; mini[r] = 0; }

    for (int T = 0; T < 16; ++T) {
        __syncthreads();                 // staged buffer ready
        if (T < 15) stage((T + 1) & 1, T + 1);
        const _Float16* bt =
            (const _Float16*)(smem + (grp * 2 + (T & 1)) * 16384);
#pragma unroll
        for (int cc = 0; cc < 2; ++cc) {
            int k = cc * 16 + col;       // local code (0..31)
            v8h bf[8];
#pragma unroll
            for (int c = 0; c < 8; ++c) {
                int u = (c * 4 + quad) ^ (col & 7);   // k&7 == col&7
                bf[c] = *(const v8h*)(bt + (size_t)k * 256 + u * 8);
            }
            v4f acc0 = {0.f, 0.f, 0.f, 0.f};
            v4f acc1 = {0.f, 0.f, 0.f, 0.f};
#pragma unroll
            for (int c = 0; c < 8; ++c) {
                acc0 = __builtin_amdgcn_mfma_f32_16x16x32_f16(af0[c], bf[c], acc0, 0, 0, 0);
                acc1 = __builtin_amdgcn_mfma_f32_16x16x32_f16(af1[c], bf[c], acc1, 0, 0, 0);
            }
            int   code = grp * 512 + T * 32 + k;
            float n    = norm_s[code];
#pragma unroll
            for (int r = 0; r < 4; ++r) {
                float d0 = n - acc0[r];
                if (d0 < minv[r])     { minv[r]     = d0; mini[r]     = code; }
                float d1 = n - acc1[r];
                if (d1 < minv[4 + r]) { minv[4 + r] = d1; mini[4 + r] = code; }
            }
        }
    }
    // reduce across the 16 cols of each quad
#pragma unroll
    for (int off = 1; off < 16; off <<= 1) {
#pragma unroll
        for (int r = 0; r < 8; ++r) {
            float ov = __shfl_xor(minv[r], off);
            int   oi = __shfl_xor(mini[r], off);
            if (ov < minv[r] || (ov == minv[r] && oi < mini[r])) {
                minv[r] = ov; mini[r] = oi;
            }
        }
    }
    // K-split merge: half-1 posts, half-0 merges (strict < keeps low idx)
    if (grp == 1 && col == 0) {
#pragma unroll
        for (int r = 0; r < 8; ++r) {
            int rl = (r >> 2) * 16 + quad * 4 + (r & 3);
            mrg[wv][rl] = make_float2(minv[r], __int_as_float(mini[r]));
        }
    }
    __syncthreads();
    if (grp == 0 && col == 0) {
#pragma unroll
        for (int r = 0; r < 8; ++r) {
            int rl = (r >> 2) * 16 + quad * 4 + (r & 3);
            float2 m2 = mrg[wv][rl];
            int mi = mini[r];
            if (m2.x < minv[r]) mi = __float_as_int(m2.y);
            idx_s[wv * 32 + rl] = mi;
        }
    }
    __syncthreads();

    // ---- epilogue: gather emb rows -> LDS, write out + fused loss ----
    // group g handles rows hw0 + g*64 .. +63 in two 32-row passes
    float* zqg = (float*)(smem + grp * 32896);   // 32 x 257 floats
    int tt = t & 255;
    float sum = 0.f;
    for (int s = 0; s < 2; ++s) {
        if (s) __syncthreads();
#pragma unroll 4
        for (int i = 0; i < 32; ++i)
            zqg[i * 257 + tt] =
                emb[(size_t)idx_s[grp * 64 + s * 32 + i] * D_DIM + tt];
        __syncthreads();
        int j = tt & 31, dq = tt >> 5;
#pragma unroll 4
        for (int p = 0; p < 32; ++p) {
            int d = dq * 32 + p;
            size_t o = (size_t)(b * D_DIM + d) * HW
                       + hw0 + grp * 64 + s * 32 + j;
            float q  = zqg[j * 257 + d];
            float e  = z[o];
            float df = q - e;
            sum += df * df;
            out[o] = q;                 // z_q_st == z_q numerically
        }
    }
    for (int off = 32; off; off >>= 1) sum += __shfl_down(sum, off);
    if (lane == 0) wred[wave] = sum;
    __syncthreads();
    if (t == 0) {
        float s8 = 0.f;
#pragma unroll
        for (int i = 0; i < 8; ++i) s8 += wred[i];
        atomicAdd(loss_acc, s8);
    }
}

// ------------------------------------------------------------------
// K3: vq_loss = 1.25 * sum / TOT_ELEMS
__global__ void finalize(const float* __restrict__ loss_acc,
                         float* __restrict__ out_loss) {
    out_loss[0] = loss_acc[0] * (1.25f / (float)TOT_ELEMS);
}

// ------------------------------------------------------------------
extern "C" void kernel_launch(void* const* d_in, const int* in_sizes, int n_in,
                              void* d_out, int out_size, void* d_ws, size_t ws_size,
                              hipStream_t stream) {
    const float* z   = (const float*)d_in[0];   // [32,256,32,32]
    const float* emb = (const float*)d_in[1];   // [1024,256]
    float* out = (float*)d_out;                 // [8388608 z_q_st][1 loss]

    char* ws = (char*)d_ws;
    float*    loss_acc = (float*)ws;            // @0 (zeroed below)
    float*    hnorm    = (float*)(ws + 1024);   // 4 KB
    _Float16* emb_h    = (_Float16*)(ws + 8192);// 512 KB

    hipMemsetAsync(d_ws, 0, 256, stream);
    prep_emb<<<dim3(K_CODES), dim3(256), 0, stream>>>(emb, emb_h, hnorm);
    vq_main<<<dim3(256), dim3(512), 0, stream>>>(z, emb_h, emb, hnorm, out, loss_acc);
    finalize<<<dim3(1), dim3(1), 0, stream>>>(loss_acc, out + TOT_ELEMS);
}

// Round 6
// 134.474 us; speedup vs baseline: 1.0477x; 1.0477x over previous
//
#include <hip/hip_runtime.h>
#include <stdint.h>
#include <stddef.h>

// ---- problem constants ----
#define K_CODES 1024
#define D_DIM   256
#define HW      1024      // 32*32 spatial
#define N_VEC   32768
#define TOT_ELEMS 8388608

typedef float    v4f __attribute__((ext_vector_type(4)));
typedef _Float16 v8h __attribute__((ext_vector_type(8)));

// async global->LDS, 16B/lane, dest = wave-uniform base + lane*16
__device__ __forceinline__ void gld_lds16(const void* g, void* l) {
    __builtin_amdgcn_global_load_lds(
        (const __attribute__((address_space(1))) void*)g,
        (__attribute__((address_space(3))) void*)l, 16, 0, 0);
}

// ------------------------------------------------------------------
// K1: codebook -> fp16 copy + 0.5*||e||^2
__global__ void prep_emb(const float* __restrict__ emb,
                         _Float16* __restrict__ emb_h,
                         float* __restrict__ hnorm) {
    int k = blockIdx.x, t = threadIdx.x;
    float v = emb[(size_t)k * D_DIM + t];
    emb_h[(size_t)k * D_DIM + t] = (_Float16)v;
    float s = v * v;
    for (int off = 32; off; off >>= 1) s += __shfl_down(s, off);
    __shared__ float wsum[4];
    if ((t & 63) == 0) wsum[t >> 6] = s;
    __syncthreads();
    if (t == 0) hnorm[k] = 0.5f * (wsum[0] + wsum[1] + wsum[2] + wsum[3]);
}

// ------------------------------------------------------------------
// K2: fused VQ. Grid 512 blocks x 512 thr (8 waves = 2 row-groups x
// 4 K-quarters), 64 rows/block -> 4096 waves = 16/CU, and LDS ~72 KB
// -> 2 blocks/CU co-resident (cross-block latency hiding).
// dist' = 0.5||e||^2 - <z,e>;  loss_row = 2*min_dist' + ||z_row||^2
// (z re-read eliminated). Staging: 16-code tiles (8 KB), dbuf/quarter.
__global__ __launch_bounds__(512, 4) void
vq_main(const float* __restrict__ z,
        const _Float16* __restrict__ emb_h,
        const float* __restrict__ emb,
        const float* __restrict__ hnorm,
        float* __restrict__ out,
        float* __restrict__ loss_acc) {
    // [0,65536): btile[4 quarters][2 buf][8KB]  | epilogue zq overlay
    // [65536,69632): norm_s[1024]               | (overlaid too; dead then)
    __shared__ __align__(16) char smem[69632];
    __shared__ int    idx_s[64];
    __shared__ float2 mrg[3][2][32];   // quarters 1..3 post results
    __shared__ float  rnorm_s[64];
    __shared__ float  wred[2];

    float* norm_s = (float*)(smem + 65536);

    int t    = threadIdx.x;
    int wave = t >> 6;
    int lane = t & 63;
    int q    = wave >> 1;     // K-quarter 0..3
    int rg   = wave & 1;      // row-group 0/1
    int col  = lane & 15;
    int quad = lane >> 4;
    int b    = blockIdx.x >> 4;
    int hw0  = (blockIdx.x & 15) * 64;
    const float* zb = z + (size_t)b * D_DIM * HW;

    // stage 16-code tile T (8 KB) of quarter q; the 2 waves sharing q
    // each stage 8 codes. granule g of code k -> slot u = g ^ (k&7).
    auto stage = [&](int buf, int T) {
        const char* src = (const char*)emb_h + (size_t)(q * 256 + T * 16) * 512;
        char* dst = smem + (q * 2 + buf) * 8192 + rg * 4096;
#pragma unroll
        for (int i = 0; i < 4; ++i) {
            int k = rg * 8 + i * 2 + (lane >> 5);
            int g = (lane & 31) ^ (k & 7);
            gld_lds16(src + (size_t)k * 512 + (size_t)g * 16, dst + i * 1024);
        }
    };
    stage(0, 0);

    for (int i = t; i < K_CODES; i += 512) norm_s[i] = hnorm[i];

    // A fragments (32 rows/wave) + fp32 row norms (q==0 only uses them)
    int m0w = hw0 + rg * 32;
    v8h af0[8], af1[8];
    float zs0 = 0.f, zs1 = 0.f;
#pragma unroll
    for (int c = 0; c < 8; ++c) {
#pragma unroll
        for (int j = 0; j < 8; ++j) {
            int d = c * 32 + quad * 8 + j;
            const float* p = zb + (size_t)d * HW + m0w + col;
            float v0 = p[0], v1 = p[16];
            af0[c][j] = (_Float16)v0;
            af1[c][j] = (_Float16)v1;
            zs0 += v0 * v0; zs1 += v1 * v1;
        }
    }
    if (q == 0) {
        zs0 += __shfl_xor(zs0, 16); zs0 += __shfl_xor(zs0, 32);
        zs1 += __shfl_xor(zs1, 16); zs1 += __shfl_xor(zs1, 32);
        if (quad == 0) {
            rnorm_s[rg * 32 + col]      = zs0;   // rows 0..15 of group
            rnorm_s[rg * 32 + 16 + col] = zs1;   // rows 16..31
        }
    }

    float minv[8]; int mini[8];
#pragma unroll
    for (int r = 0; r < 8; ++r) { minv[r] = 3.4e38f; mini[r] = 0; }

    for (int T = 0; T < 16; ++T) {
        __syncthreads();                 // staged buffer ready
        if (T < 15) stage((T + 1) & 1, T + 1);
        const _Float16* bt =
            (const _Float16*)(smem + (q * 2 + (T & 1)) * 8192);
        v8h bf[8];
#pragma unroll
        for (int c = 0; c < 8; ++c) {
            int u = (c * 4 + quad) ^ (col & 7);
            bf[c] = *(const v8h*)(bt + (size_t)col * 256 + u * 8);
        }
        v4f acc0 = {0.f, 0.f, 0.f, 0.f};
        v4f acc1 = {0.f, 0.f, 0.f, 0.f};
#pragma unroll
        for (int c = 0; c < 8; ++c) {
            acc0 = __builtin_amdgcn_mfma_f32_16x16x32_f16(af0[c], bf[c], acc0, 0, 0, 0);
            acc1 = __builtin_amdgcn_mfma_f32_16x16x32_f16(af1[c], bf[c], acc1, 0, 0, 0);
        }
        int   code = q * 256 + T * 16 + col;
        float n    = norm_s[code];
#pragma unroll
        for (int r = 0; r < 4; ++r) {
            float d0 = n - acc0[r];
            if (d0 < minv[r])     { minv[r]     = d0; mini[r]     = code; }
            float d1 = n - acc1[r];
            if (d1 < minv[4 + r]) { minv[4 + r] = d1; mini[4 + r] = code; }
        }
    }
    // reduce across the 16 cols of each quad (tie -> lower code idx)
#pragma unroll
    for (int off = 1; off < 16; off <<= 1) {
#pragma unroll
        for (int r = 0; r < 8; ++r) {
            float ov = __shfl_xor(minv[r], off);
            int   oi = __shfl_xor(mini[r], off);
            if (ov < minv[r] || (ov == minv[r] && oi < mini[r])) {
                minv[r] = ov; mini[r] = oi;
            }
        }
    }
    // quarters 1..3 post; quarter 0 merges (strict < keeps lowest idx)
    if (q >= 1 && col == 0) {
#pragma unroll
        for (int r = 0; r < 8; ++r) {
            int rl = (r >> 2) * 16 + quad * 4 + (r & 3);
            mrg[q - 1][rg][rl] = make_float2(minv[r], __int_as_float(mini[r]));
        }
    }
    __syncthreads();
    float lsum = 0.f;
    if (q == 0 && col == 0) {
#pragma unroll
        for (int r = 0; r < 8; ++r) {
            int rl = (r >> 2) * 16 + quad * 4 + (r & 3);
            float v = minv[r]; int mi = mini[r];
#pragma unroll
            for (int qq = 0; qq < 3; ++qq) {
                float2 m2 = mrg[qq][rg][rl];
                if (m2.x < v) { v = m2.x; mi = __float_as_int(m2.y); }
            }
            idx_s[rg * 32 + rl] = mi;
            lsum += 2.f * v + rnorm_s[rg * 32 + rl];
        }
    }
    for (int off = 32; off; off >>= 1) lsum += __shfl_down(lsum, off);
    if (wave < 2 && lane == 0) wred[wave] = lsum;   // waves 0,1 are q==0
    __syncthreads();
    if (t == 0) atomicAdd(loss_acc, wred[0] + wred[1]);

    // ---- epilogue: gather emb rows -> LDS (pad 257), coalesced store ----
    float* zq = (float*)smem;            // 64 x 257 floats (overlay)
#pragma unroll 4
    for (int p = 0; p < 32; ++p) {
        int row = p * 2 + (t >> 8);
        int d   = t & 255;
        zq[row * 257 + d] = emb[(size_t)idx_s[row] * D_DIM + d];
    }
    __syncthreads();
#pragma unroll 4
    for (int p = 0; p < 32; ++p) {
        int d   = p * 8 + (t >> 6);
        int hwl = t & 63;
        out[(size_t)(b * D_DIM + d) * HW + hw0 + hwl] = zq[hwl * 257 + d];
    }
}

// ------------------------------------------------------------------
// K3: vq_loss = 1.25 * sum / TOT_ELEMS
__global__ void finalize(const float* __restrict__ loss_acc,
                         float* __restrict__ out_loss) {
    out_loss[0] = loss_acc[0] * (1.25f / (float)TOT_ELEMS);
}

// ------------------------------------------------------------------
extern "C" void kernel_launch(void* const* d_in, const int* in_sizes, int n_in,
                              void* d_out, int out_size, void* d_ws, size_t ws_size,
                              hipStream_t stream) {
    const float* z   = (const float*)d_in[0];   // [32,256,32,32]
    const float* emb = (const float*)d_in[1];   // [1024,256]
    float* out = (float*)d_out;                 // [8388608 z_q_st][1 loss]

    char* ws = (char*)d_ws;
    float*    loss_acc = (float*)ws;            // @0 (zeroed below)
    float*    hnorm    = (float*)(ws + 1024);   // 4 KB
    _Float16* emb_h    = (_Float16*)(ws + 8192);// 512 KB

    hipMemsetAsync(d_ws, 0, 256, stream);
    prep_emb<<<dim3(K_CODES), dim3(256), 0, stream>>>(emb, emb_h, hnorm);
    vq_main<<<dim3(512), dim3(512), 0, stream>>>(z, emb_h, emb, hnorm, out, loss_acc);
    finalize<<<dim3(1), dim3(1), 0, stream>>>(loss_acc, out + TOT_ELEMS);
}